// Round 1
// baseline (149.364 us; speedup 1.0000x reference)
//
#include <hip/hip_runtime.h>
#include <math.h>

// Problem constants (fixed by setup_inputs)
#define D     1024   // gd = dn = de
#define N1    48     // n1 = n2
#define E1    192    // e1 = e2
#define NOUT  2304   // n1*n2 = output dim
#define NE    36864  // e1*e2

// ---------------------------------------------------------------------------
// coeff = tanh(W @ gw + b) for both node (rows 0..1023) and edge (1024..2047)
// One block (256 thr) per output row: 1024-dot via float4 + wave/LDS reduce.
// ---------------------------------------------------------------------------
__global__ void coeff_kernel(const float* __restrict__ Wn, const float* __restrict__ bn,
                             const float* __restrict__ We, const float* __restrict__ be,
                             const float* __restrict__ gw, float* __restrict__ coeff) {
    int row = blockIdx.x;
    const float* W; const float* b; int d;
    if (row < D) { W = Wn; b = bn; d = row; }
    else         { W = We; b = be; d = row - D; }
    int t = threadIdx.x;
    float4 w = *(const float4*)(W + (size_t)d * D + t * 4);
    float4 g = *(const float4*)(gw + t * 4);
    float s = w.x * g.x + w.y * g.y + w.z * g.z + w.w * g.w;
    #pragma unroll
    for (int off = 32; off > 0; off >>= 1) s += __shfl_down(s, off);
    __shared__ float red[4];
    if ((t & 63) == 0) red[t >> 6] = s;
    __syncthreads();
    if (t == 0) {
        float tot = red[0] + red[1] + red[2] + red[3];
        coeff[row] = tanhf(tot + b[d]);
    }
}

// ---------------------------------------------------------------------------
// out[i,j] = relu(softplus(sum_d A[i,d]*coeff[d]*B[j,d]) - 0.5)
// 16x16 output tile per 256-thread block; K staged through LDS in chunks of
// 64, coeff multiplied into the A tile at load. Row pad 68 (=64+4): keeps
// 16B alignment for ds_read_b128 and breaks the stride-64 bank aliasing
// (bank stride 4 -> only free 2-way conflicts).
// ---------------------------------------------------------------------------
__global__ void affinity_kernel(const float* __restrict__ A, const float* __restrict__ B,
                                const float* __restrict__ coeff, float* __restrict__ out,
                                int ncols) {
    __shared__ float As[16][68];
    __shared__ float Bs[16][68];
    int t  = threadIdx.x;
    int r  = t >> 4;          // 0..15, tile row this thread loads / computes
    int cb = (t & 15) << 2;   // 0..60, k-chunk column base for loads
    int tx = t & 15;          // tile col this thread computes
    size_t rowA = (size_t)(blockIdx.y * 16 + r);
    size_t rowB = (size_t)(blockIdx.x * 16 + r);
    float acc = 0.f;
    for (int k0 = 0; k0 < D; k0 += 64) {
        float4 a = *(const float4*)(A + rowA * D + k0 + cb);
        float4 c = *(const float4*)(coeff + k0 + cb);
        float4 b = *(const float4*)(B + rowB * D + k0 + cb);
        *(float4*)&As[r][cb] = make_float4(a.x * c.x, a.y * c.y, a.z * c.z, a.w * c.w);
        *(float4*)&Bs[r][cb] = b;
        __syncthreads();
        #pragma unroll
        for (int kk = 0; kk < 64; kk += 4) {
            float4 av = *(const float4*)&As[r][kk];
            float4 bv = *(const float4*)&Bs[tx][kk];
            acc = fmaf(av.x, bv.x, acc);
            acc = fmaf(av.y, bv.y, acc);
            acc = fmaf(av.z, bv.z, acc);
            acc = fmaf(av.w, bv.w, acc);
        }
        __syncthreads();
    }
    // stable softplus, then -0.5 and relu
    float sp = fmaxf(acc, 0.f) + log1pf(expf(-fabsf(acc)));
    float v  = fmaxf(sp - 0.5f, 0.f);
    out[(size_t)(blockIdx.y * 16 + r) * ncols + blockIdx.x * 16 + tx] = v;
}

// ---------------------------------------------------------------------------
// M = 0 everywhere except M[r,r] = Mp_flat[r]. float4 stores (2304 % 4 == 0).
// ---------------------------------------------------------------------------
__global__ void init_out_kernel(float* __restrict__ M, const float* __restrict__ Mp) {
    int idx = blockIdx.x * blockDim.x + threadIdx.x;   // over 2304 * 576
    if (idx >= NOUT * (NOUT / 4)) return;
    int r = idx / (NOUT / 4);
    int c = (idx - r * (NOUT / 4)) << 2;
    float4 v = make_float4(0.f, 0.f, 0.f, 0.f);
    int d = r - c;
    if (d >= 0 && d < 4) ((float*)&v)[d] = Mp[r];
    *(float4*)(M + (size_t)r * NOUT + c) = v;
}

// ---------------------------------------------------------------------------
// Kron scatter: q = b2*e1 + b1 ->
//   M[h2[b2]*48 + h1[b1], t2[b2]*48 + t1[b1]] += Me_flat[q]
// edge_index layout: [0..E1) = heads (row 0), [E1..2*E1) = tails (row 1).
// ---------------------------------------------------------------------------
__global__ void scatter_kernel(float* __restrict__ M, const float* __restrict__ Me,
                               const int* __restrict__ ei1, const int* __restrict__ ei2) {
    int q = blockIdx.x * blockDim.x + threadIdx.x;
    if (q >= NE) return;
    int b2 = q / E1;
    int b1 = q - b2 * E1;
    int r = ei2[b2]      * N1 + ei1[b1];
    int c = ei2[E1 + b2] * N1 + ei1[E1 + b1];
    atomicAdd(M + (size_t)r * NOUT + c, Me[q]);
}

extern "C" void kernel_launch(void* const* d_in, const int* in_sizes, int n_in,
                              void* d_out, int out_size, void* d_ws, size_t ws_size,
                              hipStream_t stream) {
    const float* x1  = (const float*)d_in[0];
    const float* x2  = (const float*)d_in[1];
    const float* ef1 = (const float*)d_in[2];
    const float* ef2 = (const float*)d_in[3];
    const float* gw  = (const float*)d_in[4];
    const float* Wn  = (const float*)d_in[5];
    const float* bn  = (const float*)d_in[6];
    const float* We  = (const float*)d_in[7];
    const float* be  = (const float*)d_in[8];
    const int*   ei1 = (const int*)d_in[9];
    const int*   ei2 = (const int*)d_in[10];

    float* M  = (float*)d_out;
    float* ws = (float*)d_ws;
    float* coeff = ws;              // [0..1024) node coeff, [1024..2048) edge coeff
    float* Mp    = ws + 2048;       // 2304 floats
    float* Me    = ws + 2048 + NOUT; // 36864 floats

    coeff_kernel<<<2 * D, 256, 0, stream>>>(Wn, bn, We, be, gw, coeff);
    affinity_kernel<<<dim3(N1 / 16, N1 / 16), 256, 0, stream>>>(x1, x2, coeff, Mp, N1);
    affinity_kernel<<<dim3(E1 / 16, E1 / 16), 256, 0, stream>>>(ef1, ef2, coeff + D, Me, E1);
    init_out_kernel<<<(NOUT * (NOUT / 4) + 255) / 256, 256, 0, stream>>>(M, Mp);
    scatter_kernel<<<(NE + 255) / 256, 256, 0, stream>>>(M, Me, ei1, ei2);
}

// Round 2
// 112.684 us; speedup vs baseline: 1.3255x; 1.3255x over previous
//
#include <hip/hip_runtime.h>
#include <math.h>

// Problem constants (fixed by setup_inputs)
#define D     1024   // gd = dn = de
#define N1    48     // n1 = n2
#define E1    192    // e1 = e2
#define NOUT  2304   // n1*n2 = output dim
#define NE    36864  // e1*e2
#define KS    8      // K-split factor (K=128 per block slice)

// ---------------------------------------------------------------------------
// coeff = tanh(W @ gw + b) for both node (rows 0..1023) and edge (1024..2047)
// One block (256 thr) per output row: 1024-dot via float4 + wave/LDS reduce.
// ---------------------------------------------------------------------------
__global__ void coeff_kernel(const float* __restrict__ Wn, const float* __restrict__ bn,
                             const float* __restrict__ We, const float* __restrict__ be,
                             const float* __restrict__ gw, float* __restrict__ coeff) {
    int row = blockIdx.x;
    const float* W; const float* b; int d;
    if (row < D) { W = Wn; b = bn; d = row; }
    else         { W = We; b = be; d = row - D; }
    int t = threadIdx.x;
    float4 w = *(const float4*)(W + (size_t)d * D + t * 4);
    float4 g = *(const float4*)(gw + t * 4);
    float s = w.x * g.x + w.y * g.y + w.z * g.z + w.w * g.w;
    #pragma unroll
    for (int off = 32; off > 0; off >>= 1) s += __shfl_down(s, off);
    __shared__ float red[4];
    if ((t & 63) == 0) red[t >> 6] = s;
    __syncthreads();
    if (t == 0) {
        float tot = red[0] + red[1] + red[2] + red[3];
        coeff[row] = tanhf(tot + b[d]);
    }
}

// ---------------------------------------------------------------------------
// Split-K affinity partials for BOTH matrices in one launch.
// Block decode: [0,72) -> Mp tiles (3x3 tiles x 8 kslices), [72,1224) -> Me
// (12x12 tiles x 8 kslices). Each block: 16x16 output tile, K=128 slice
// (2 LDS chunks of 64). Raw dot partials (no activation) -> private slice,
// so no atomics and no zero-init of ws needed.
// Row pad 68 keeps 16B alignment for ds_read_b128; bank stride 4 -> only
// free 2-way conflicts on the Bs reads.
// ---------------------------------------------------------------------------
__global__ void affinity_partial_kernel(const float* __restrict__ x1, const float* __restrict__ x2,
                                        const float* __restrict__ ef1, const float* __restrict__ ef2,
                                        const float* __restrict__ coeff,
                                        float* __restrict__ Mp_part, float* __restrict__ Me_part) {
    __shared__ float As[16][68];
    __shared__ float Bs[16][68];
    int bid = blockIdx.x;
    const float *A, *B, *cf; float* out; int ncols, tiles_x, tile, ks;
    if (bid < 9 * KS) {
        tile = bid >> 3; ks = bid & 7;
        A = x1; B = x2; cf = coeff; out = Mp_part + ks * NOUT; ncols = N1; tiles_x = 3;
    } else {
        int b = bid - 9 * KS;
        tile = b >> 3; ks = b & 7;
        A = ef1; B = ef2; cf = coeff + D; out = Me_part + ks * NE; ncols = E1; tiles_x = 12;
    }
    int ty = tile / tiles_x, tx = tile - ty * tiles_x;

    int t  = threadIdx.x;
    int r  = t >> 4;          // 0..15: tile row (load + compute)
    int cb = (t & 15) << 2;   // 0..60: k-column base for loads
    int cc = t & 15;          // 0..15: tile col (compute)
    size_t rowA = (size_t)(ty * 16 + r);
    size_t rowB = (size_t)(tx * 16 + r);
    float acc = 0.f;
    #pragma unroll
    for (int ch = 0; ch < 2; ch++) {
        int k0 = ks * 128 + ch * 64;
        float4 a = *(const float4*)(A + rowA * D + k0 + cb);
        float4 c = *(const float4*)(cf + k0 + cb);
        float4 b = *(const float4*)(B + rowB * D + k0 + cb);
        *(float4*)&As[r][cb] = make_float4(a.x * c.x, a.y * c.y, a.z * c.z, a.w * c.w);
        *(float4*)&Bs[r][cb] = b;
        __syncthreads();
        #pragma unroll
        for (int kk = 0; kk < 64; kk += 4) {
            float4 av = *(const float4*)&As[r][kk];
            float4 bv = *(const float4*)&Bs[cc][kk];
            acc = fmaf(av.x, bv.x, acc);
            acc = fmaf(av.y, bv.y, acc);
            acc = fmaf(av.z, bv.z, acc);
            acc = fmaf(av.w, bv.w, acc);
        }
        __syncthreads();
    }
    out[(size_t)(ty * 16 + r) * ncols + tx * 16 + cc] = acc;
}

__device__ __forceinline__ float act(float x) {
    float sp = fmaxf(x, 0.f) + log1pf(expf(-fabsf(x)));   // stable softplus
    return fmaxf(sp - 0.5f, 0.f);
}

// ---------------------------------------------------------------------------
// M = 0 everywhere except M[r,r] = act(sum_ks Mp_part[ks][r]). float4 stores.
// ---------------------------------------------------------------------------
__global__ void init_out_kernel(float* __restrict__ M, const float* __restrict__ Mp_part) {
    int idx = blockIdx.x * blockDim.x + threadIdx.x;   // over 2304 * 576
    if (idx >= NOUT * (NOUT / 4)) return;
    int r = idx / (NOUT / 4);
    int c = (idx - r * (NOUT / 4)) << 2;
    float4 v = make_float4(0.f, 0.f, 0.f, 0.f);
    int d = r - c;
    if (d >= 0 && d < 4) {
        float s = 0.f;
        #pragma unroll
        for (int ks = 0; ks < KS; ks++) s += Mp_part[ks * NOUT + r];
        ((float*)&v)[d] = act(s);
    }
    *(float4*)(M + (size_t)r * NOUT + c) = v;
}

// ---------------------------------------------------------------------------
// Kron scatter: q = b2*e1 + b1 ->
//   M[h2[b2]*48 + h1[b1], t2[b2]*48 + t1[b1]] += act(sum_ks Me_part[ks][q])
// Skip the atomic when the relu output is exactly 0 (~half of all q).
// ---------------------------------------------------------------------------
__global__ void scatter_kernel(float* __restrict__ M, const float* __restrict__ Me_part,
                               const int* __restrict__ ei1, const int* __restrict__ ei2) {
    int q = blockIdx.x * blockDim.x + threadIdx.x;
    if (q >= NE) return;
    float s = 0.f;
    #pragma unroll
    for (int ks = 0; ks < KS; ks++) s += Me_part[ks * NE + q];
    float v = act(s);
    if (v > 0.f) {
        int b2 = q / E1;
        int b1 = q - b2 * E1;
        int r = ei2[b2]      * N1 + ei1[b1];
        int c = ei2[E1 + b2] * N1 + ei1[E1 + b1];
        atomicAdd(M + (size_t)r * NOUT + c, v);
    }
}

extern "C" void kernel_launch(void* const* d_in, const int* in_sizes, int n_in,
                              void* d_out, int out_size, void* d_ws, size_t ws_size,
                              hipStream_t stream) {
    const float* x1  = (const float*)d_in[0];
    const float* x2  = (const float*)d_in[1];
    const float* ef1 = (const float*)d_in[2];
    const float* ef2 = (const float*)d_in[3];
    const float* gw  = (const float*)d_in[4];
    const float* Wn  = (const float*)d_in[5];
    const float* bn  = (const float*)d_in[6];
    const float* We  = (const float*)d_in[7];
    const float* be  = (const float*)d_in[8];
    const int*   ei1 = (const int*)d_in[9];
    const int*   ei2 = (const int*)d_in[10];

    float* M  = (float*)d_out;
    float* ws = (float*)d_ws;
    float* coeff   = ws;                         // 2048 floats
    float* Mp_part = ws + 2048;                  // KS * 2304
    float* Me_part = Mp_part + KS * NOUT;        // KS * 36864

    coeff_kernel<<<2 * D, 256, 0, stream>>>(Wn, bn, We, be, gw, coeff);
    affinity_partial_kernel<<<(9 + 144) * KS, 256, 0, stream>>>(x1, x2, ef1, ef2, coeff,
                                                                Mp_part, Me_part);
    init_out_kernel<<<(NOUT * (NOUT / 4) + 255) / 256, 256, 0, stream>>>(M, Mp_part);
    scatter_kernel<<<(NE + 255) / 256, 256, 0, stream>>>(M, Me_part, ei1, ei2);
}

// Round 3
// 94.421 us; speedup vs baseline: 1.5819x; 1.1934x over previous
//
#include <hip/hip_runtime.h>
#include <math.h>

// Problem constants (fixed by setup_inputs)
#define D     1024   // gd = dn = de
#define N1    48     // n1 = n2
#define E1    192    // e1 = e2
#define NOUT  2304   // n1*n2 = output dim
#define NE    36864  // e1*e2
#define KS    8      // K-split factor (K=128 per block slice)

#define AFF_BLOCKS  ((9 + 144) * KS)          // 1224
#define ZERO_BLOCKS (NOUT * NOUT / 4096)      // 1296 (4096 floats per block)
#define SCAT_BLOCKS (NE / 256)                // 144
#define DIAG_BLOCKS (NOUT / 256)              // 9

// ---------------------------------------------------------------------------
// K1: coeff = tanh(W @ gw + b); rows [0,1024) node, [1024,2048) edge.
// One block (256 thr) per row: 1024-dot via float4 + wave/LDS reduce.
// ---------------------------------------------------------------------------
__global__ void coeff_kernel(const float* __restrict__ Wn, const float* __restrict__ bn,
                             const float* __restrict__ We, const float* __restrict__ be,
                             const float* __restrict__ gw, float* __restrict__ coeff) {
    int row = blockIdx.x;
    const float* W; const float* b; int d;
    if (row < D) { W = Wn; b = bn; d = row; }
    else         { W = We; b = be; d = row - D; }
    int t = threadIdx.x;
    float4 w = *(const float4*)(W + (size_t)d * D + t * 4);
    float4 g = *(const float4*)(gw + t * 4);
    float s = w.x * g.x + w.y * g.y + w.z * g.z + w.w * g.w;
    #pragma unroll
    for (int off = 32; off > 0; off >>= 1) s += __shfl_down(s, off);
    __shared__ float red[4];
    if ((t & 63) == 0) red[t >> 6] = s;
    __syncthreads();
    if (t == 0) {
        float tot = red[0] + red[1] + red[2] + red[3];
        coeff[row] = tanhf(tot + b[d]);
    }
}

// ---------------------------------------------------------------------------
// K2: fused (a) split-K affinity partials for both matrices and (b) zero-fill
// of the 21 MB output M. Disjoint block ranges -> the pure-write zeroing
// overlaps the read/LDS-bound affinity compute.
//   blocks [0, 1224): affinity. 16x16 tile, K=128 slice (2 LDS chunks of 64).
//   blocks [1224, 2520): M zeroing, 4096 floats/block, coalesced float4.
// Raw dot partials -> private ks slice: no atomics, no ws zero-init needed.
// ---------------------------------------------------------------------------
__global__ void affinity_zero_kernel(const float* __restrict__ x1, const float* __restrict__ x2,
                                     const float* __restrict__ ef1, const float* __restrict__ ef2,
                                     const float* __restrict__ coeff,
                                     float* __restrict__ Mp_part, float* __restrict__ Me_part,
                                     float* __restrict__ M) {
    __shared__ float As[16][68];
    __shared__ float Bs[16][68];
    int bid = blockIdx.x;
    int t = threadIdx.x;

    if (bid >= AFF_BLOCKS) {
        // ---- zero-fill branch: block covers 4096 consecutive floats of M
        size_t base = (size_t)(bid - AFF_BLOCKS) * 4096 + t * 4;
        float4 z = make_float4(0.f, 0.f, 0.f, 0.f);
        #pragma unroll
        for (int p = 0; p < 4; p++)
            *(float4*)(M + base + p * 1024) = z;
        return;
    }

    const float *A, *B, *cf; float* out; int ncols, tiles_x, tile, ks;
    if (bid < 9 * KS) {
        tile = bid >> 3; ks = bid & 7;
        A = x1; B = x2; cf = coeff; out = Mp_part + ks * NOUT; ncols = N1; tiles_x = 3;
    } else {
        int b = bid - 9 * KS;
        tile = b >> 3; ks = b & 7;
        A = ef1; B = ef2; cf = coeff + D; out = Me_part + ks * NE; ncols = E1; tiles_x = 12;
    }
    int ty = tile / tiles_x, tx = tile - ty * tiles_x;

    int r  = t >> 4;          // 0..15: tile row (load + compute)
    int cb = (t & 15) << 2;   // 0..60: k-column base for loads
    int cc = t & 15;          // 0..15: tile col (compute)
    size_t rowA = (size_t)(ty * 16 + r);
    size_t rowB = (size_t)(tx * 16 + r);
    float acc = 0.f;
    #pragma unroll
    for (int ch = 0; ch < 2; ch++) {
        int k0 = ks * 128 + ch * 64;
        float4 a = *(const float4*)(A + rowA * D + k0 + cb);
        float4 c = *(const float4*)(cf + k0 + cb);
        float4 b = *(const float4*)(B + rowB * D + k0 + cb);
        *(float4*)&As[r][cb] = make_float4(a.x * c.x, a.y * c.y, a.z * c.z, a.w * c.w);
        *(float4*)&Bs[r][cb] = b;
        __syncthreads();
        #pragma unroll
        for (int kk = 0; kk < 64; kk += 4) {
            float4 av = *(const float4*)&As[r][kk];
            float4 bv = *(const float4*)&Bs[cc][kk];
            acc = fmaf(av.x, bv.x, acc);
            acc = fmaf(av.y, bv.y, acc);
            acc = fmaf(av.z, bv.z, acc);
            acc = fmaf(av.w, bv.w, acc);
        }
        __syncthreads();
    }
    out[(size_t)(ty * 16 + r) * ncols + tx * 16 + cc] = acc;
}

__device__ __forceinline__ float act(float x) {
    float sp = fmaxf(x, 0.f) + log1pf(expf(-fabsf(x)));   // stable softplus
    return fmaxf(sp - 0.5f, 0.f);
}

// ---------------------------------------------------------------------------
// K3: fused scatter + diagonal. All additions via atomicAdd onto the zeroed M
// (order-independent, so diag and scatter can share one launch even when a
// self-loop edge pair lands on the diagonal).
//   blocks [0, 144): q = b2*e1 + b1 ->
//     M[h2[b2]*48+h1[b1], t2[b2]*48+t1[b1]] += act(sum_ks Me_part[ks][q])
//     (skip atomic when relu output is exactly 0, ~half of all q)
//   blocks [144, 153): M[r,r] += act(sum_ks Mp_part[ks][r])
// ---------------------------------------------------------------------------
__global__ void scatter_diag_kernel(float* __restrict__ M,
                                    const float* __restrict__ Mp_part,
                                    const float* __restrict__ Me_part,
                                    const int* __restrict__ ei1, const int* __restrict__ ei2) {
    int bid = blockIdx.x;
    int t = threadIdx.x;
    if (bid < SCAT_BLOCKS) {
        int q = bid * 256 + t;
        float s = 0.f;
        #pragma unroll
        for (int ks = 0; ks < KS; ks++) s += Me_part[ks * NE + q];
        float v = act(s);
        if (v > 0.f) {
            int b2 = q / E1;
            int b1 = q - b2 * E1;
            int r = ei2[b2]      * N1 + ei1[b1];
            int c = ei2[E1 + b2] * N1 + ei1[E1 + b1];
            atomicAdd(M + (size_t)r * NOUT + c, v);
        }
    } else {
        int r = (bid - SCAT_BLOCKS) * 256 + t;
        float s = 0.f;
        #pragma unroll
        for (int ks = 0; ks < KS; ks++) s += Mp_part[ks * NOUT + r];
        float v = act(s);
        if (v > 0.f) atomicAdd(M + (size_t)r * NOUT + r, v);
    }
}

extern "C" void kernel_launch(void* const* d_in, const int* in_sizes, int n_in,
                              void* d_out, int out_size, void* d_ws, size_t ws_size,
                              hipStream_t stream) {
    const float* x1  = (const float*)d_in[0];
    const float* x2  = (const float*)d_in[1];
    const float* ef1 = (const float*)d_in[2];
    const float* ef2 = (const float*)d_in[3];
    const float* gw  = (const float*)d_in[4];
    const float* Wn  = (const float*)d_in[5];
    const float* bn  = (const float*)d_in[6];
    const float* We  = (const float*)d_in[7];
    const float* be  = (const float*)d_in[8];
    const int*   ei1 = (const int*)d_in[9];
    const int*   ei2 = (const int*)d_in[10];

    float* M  = (float*)d_out;
    float* ws = (float*)d_ws;
    float* coeff   = ws;                         // 2048 floats
    float* Mp_part = ws + 2048;                  // KS * 2304
    float* Me_part = Mp_part + KS * NOUT;        // KS * 36864

    coeff_kernel<<<2 * D, 256, 0, stream>>>(Wn, bn, We, be, gw, coeff);
    affinity_zero_kernel<<<AFF_BLOCKS + ZERO_BLOCKS, 256, 0, stream>>>(
        x1, x2, ef1, ef2, coeff, Mp_part, Me_part, M);
    scatter_diag_kernel<<<SCAT_BLOCKS + DIAG_BLOCKS, 256, 0, stream>>>(
        M, Mp_part, Me_part, ei1, ei2);
}